// Round 12
// baseline (341.297 us; speedup 1.0000x reference)
//
#include <hip/hip_runtime.h>
#include <hip/hip_bf16.h>
#include <math.h>

// Problem constants (fixed by setup_inputs)
#define BS     8
#define LQ     1000
#define DMODEL 256
#define NH     8
#define NLV    4
#define NPT    4
#define LEN_V  8500          // 80*80+40*40+20*20+10*10
#define NQ     (BS*LQ)       // 8000
#define MV     (BS*LEN_V)    // 68000
#define KS     8             // K=256 / 32 per mfma step

typedef __attribute__((ext_vector_type(8))) short short8;     // 8 bf16 (4 VGPRs)
typedef __attribute__((ext_vector_type(4))) float floatx4;

static __device__ __forceinline__ unsigned short f2bf(float f) {
    __hip_bfloat16 h = __float2bfloat16(f);   // RNE
    return __builtin_bit_cast(unsigned short, h);
}
static __device__ __forceinline__ float asf(unsigned int u) {
    return __builtin_bit_cast(float, u);
}

// ---------------------------------------------------------------------------
// MULTI-TILE MFMA GEMM with register prefetch across raw barriers.
// r10/r11 isolated the bottleneck: one-tile blocks give HBM only ~35% duty
// (103MB @ 2.2 TB/s = 46us; cutting bytes 133->103MB didn't move time).
// Each block now runs 3 tiles; tile t+1's float4 loads fly during tile t's
// cvt+K-loop. __syncthreads would drain vmcnt(0) at the barrier (m97 stall),
// so the loop uses lgkmcnt(0) + raw s_barrier + sched_barrier(0): LDS
// visibility is guaranteed, register loads stay in flight across the barrier.
// Two static register sets (raA/raB) -- no dynamic reg indexing (rule #20).
// ---------------------------------------------------------------------------
static __device__ __forceinline__ void issue_tileA(
    const float* __restrict__ A, int bm, int M, int tid, float4 (&ra)[8][2])
{
    #pragma unroll
    for (int j = 0; j < 8; ++j) {
        const int slot = j * 256 + tid;
        const int row  = slot >> 5;
        const int gc   = (slot & 31) ^ (row & 7);     // pre-swizzled source chunk
        int grow = bm * 64 + row; grow = grow < M ? grow : M - 1;
        const float* s = A + (size_t)grow * 256 + gc * 8;
        ra[j][0] = *(const float4*)s;
        ra[j][1] = *(const float4*)(s + 4);
    }
}

static __device__ __forceinline__ void cvt_write(
    const float4 (&ra)[8][2], unsigned short* As, int tid)
{
    #pragma unroll
    for (int j = 0; j < 8; ++j) {
        short8 o;
        o[0] = (short)f2bf(ra[j][0].x); o[1] = (short)f2bf(ra[j][0].y);
        o[2] = (short)f2bf(ra[j][0].z); o[3] = (short)f2bf(ra[j][0].w);
        o[4] = (short)f2bf(ra[j][1].x); o[5] = (short)f2bf(ra[j][1].y);
        o[6] = (short)f2bf(ra[j][1].z); o[7] = (short)f2bf(ra[j][1].w);
        *(short8*)&As[(j * 256 + tid) * 8] = o;
    }
}

// barrier that does NOT drain vmcnt: LDS-visibility wait + raw s_barrier,
// pinned against compiler motion (memory clobber = IR fence, sched_barrier(0)
// = machine-scheduler fence).
static __device__ __forceinline__ void lds_barrier()
{
    asm volatile("s_waitcnt lgkmcnt(0)" ::: "memory");
    __builtin_amdgcn_s_barrier();
    __builtin_amdgcn_sched_barrier(0);
}

static __device__ __forceinline__ void gemm_group(
    const float* __restrict__ Aptr, const unsigned short* __restrict__ Bfrag,
    const float* __restrict__ bias1, const float* __restrict__ bias2, int nsplit,
    void* __restrict__ Cptr, int M, int N, int bn, int g0, int nt,
    bool outbf, unsigned short* As /* 16384 shorts = 32KB */)
{
    const int tid = threadIdx.x;
    const int l   = tid & 63;
    const int w   = tid >> 6;          // wave = column quarter (0..3)
    const int lm  = l & 15;
    const int lk  = l >> 4;
    const int x7  = lm & 7;

    // first tile's loads start immediately
    float4 raA[8][2], raB[8][2];
    issue_tileA(Aptr, g0, M, tid, raA);

    // B fragments fly under the A loads (fragment buffer is L2-hot; compiler
    // may demote them to reloads -- proven harmless, r11 VGPR=64 @ 46us)
    short8 Bf[2][KS];
    const int u0 = bn * 8 + w * 2;
    #pragma unroll
    for (int j = 0; j < 2; ++j)
        #pragma unroll
        for (int s = 0; s < KS; ++s)
            Bf[j][s] = *(const short8*)(Bfrag + ((size_t)((u0 + j) * KS + s) * 64 + l) * 8);

    bool useA = true;
    for (int i = 0; i < nt; ++i) {
        const int bm = g0 + i;

        // prefetch next tile into the OTHER reg set, then drain current->LDS.
        // (static reg references in each arm; branch is block-uniform)
        if (useA) {
            if (i + 1 < nt) issue_tileA(Aptr, bm + 1, M, tid, raB);
            cvt_write(raA, As, tid);
        } else {
            if (i + 1 < nt) issue_tileA(Aptr, bm + 1, M, tid, raA);
            cvt_write(raB, As, tid);
        }
        useA = !useA;
        lds_barrier();                 // writes visible; prefetch stays in flight

        floatx4 acc[4][2];
        #pragma unroll
        for (int ii = 0; ii < 4; ++ii)
            #pragma unroll
            for (int j = 0; j < 2; ++j)
                #pragma unroll
                for (int r = 0; r < 4; ++r) acc[ii][j][r] = 0.f;

        #pragma unroll
        for (int s = 0; s < KS; ++s) {
            short8 afr[4];
            #pragma unroll
            for (int ii = 0; ii < 4; ++ii)
                afr[ii] = *(const short8*)(
                    &As[(ii * 16 + lm) * 256 + (((s * 4 + lk) ^ x7)) * 8]);
            #pragma unroll
            for (int ii = 0; ii < 4; ++ii)
                #pragma unroll
                for (int j = 0; j < 2; ++j)
                    acc[ii][j] = __builtin_amdgcn_mfma_f32_16x16x32_bf16(
                                    afr[ii], Bf[j][s], acc[ii][j], 0, 0, 0);
        }

        #pragma unroll
        for (int j = 0; j < 2; ++j) {
            const int col = bn * 128 + w * 32 + j * 16 + lm;
            const float bv = (bias2 != nullptr && col >= nsplit) ? bias2[col - nsplit]
                                                                 : bias1[col];
            #pragma unroll
            for (int ii = 0; ii < 4; ++ii) {
                const int rbase = bm * 64 + ii * 16 + lk * 4;
                #pragma unroll
                for (int r = 0; r < 4; ++r) {
                    const int row = rbase + r;
                    if (row < M) {
                        const float v = acc[ii][j][r] + bv;
                        if (outbf)
                            ((unsigned short*)Cptr)[(size_t)row * N + col] = f2bf(v);
                        else
                            ((float*)Cptr)[(size_t)row * N + col] = v;
                    }
                }
            }
        }

        lds_barrier();                 // all reads done before next overwrite
    }
}

// ---- fused GEMMs, 3 tiles per block, register-prefetch pipeline:
//      v-proj : 710 blocks = 355 tile-groups x 2 col-halves (A=value)
//               groups of 3 over 1063 M-tiles (last group nt=1)
//      offattn: 126 blocks =  42 tile-groups x 3 col-thirds (A=query)
//               groups of 3 over  125 M-tiles (last group nt=2) ----
__global__ __launch_bounds__(256, 3) void gemm_fused(
    const float* __restrict__ value, const float* __restrict__ query,
    const unsigned short* __restrict__ wv_f, const unsigned short* __restrict__ woa_f,
    const float* __restrict__ b_v, const float* __restrict__ b_off,
    const float* __restrict__ b_attn,
    unsigned short* __restrict__ v_proj, float* __restrict__ offattn)
{
    __shared__ unsigned short As[16384];
    const int bx = blockIdx.x;
    if (bx < 710) {
        const int grp = bx >> 1, half = bx & 1;
        const int g0 = grp * 3;
        const int nt = min(3, 1063 - g0);
        gemm_group(value, wv_f, b_v, nullptr, 1 << 30,
                   v_proj, MV, 256, half, g0, nt, true, As);
    } else {
        const int ob = bx - 710;
        const int third = ob % 3, grp = ob / 3;
        const int g0 = grp * 3;
        const int nt = min(3, 125 - g0);
        gemm_group(query, woa_f, b_off, b_attn, 256,
                   offattn, NQ, 384, third, g0, nt, false, As);
    }
}

// ---- prep: weight transform to MFMA fragment layout (112 blocks, tiny) ----
__global__ __launch_bounds__(256) void prep_w(
    const float* __restrict__ w_v, const float* __restrict__ w_off,
    const float* __restrict__ w_attn, const float* __restrict__ w_o,
    unsigned short* __restrict__ wv_f, unsigned short* __restrict__ woa_f,
    unsigned short* __restrict__ wo_f)
{
    const int gid = blockIdx.x * 256 + threadIdx.x;     // 28672 total, exact
    int chunk, mode;
    if (gid < 8192)               { chunk = gid;         mode = 0; }
    else if (gid < 8192 + 12288)  { chunk = gid - 8192;  mode = 1; }
    else                          { chunk = gid - 20480; mode = 2; }
    const int l = chunk & 63, s = (chunk >> 6) & 7, u = chunk >> 9;
    short8 o;
    #pragma unroll
    for (int j = 0; j < 8; ++j) {
        const int k = s * 32 + (l >> 4) * 8 + j;
        const int n = u * 16 + (l & 15);
        float v;
        if (mode == 0)      v = w_v[k * 256 + n];
        else if (mode == 1) v = (n < 256) ? w_off[k * 256 + n] : w_attn[k * 128 + (n - 256)];
        else                v = w_o[k * 256 + n];
        o[j] = (short)f2bf(v);
    }
    unsigned short* dp = (mode == 0 ? wv_f : mode == 1 ? woa_f : wo_f)
                         + ((size_t)(u * 8 + s) * 64 + l) * 8;
    *(short8*)dp = o;
}

// ---------------- softmax + sampling + OUT-PROJECTION (512 thr) ----------------
// r11-proven 4-channel sampler, byte-identical. Wave = 1 query, lane = one
// 4-channel slot; 16 points x uint2 gathers; pA -> MFMA out-proj -> fp32 out.
// NO launch-bounds cap (r5/r8: forced caps spill catastrophically).
__global__ __launch_bounds__(512) void ms_sample_out(
    const unsigned short* __restrict__ v,    // [BS,8500,256] bf16
    const float* __restrict__ offattn,       // [NQ,384]: offs[0:256) | logits[256:384)
    const float* __restrict__ refp,          // [NQ,4,2]
    const unsigned short* __restrict__ wo_f, // w_o fragments
    const float* __restrict__ b_o,
    float* __restrict__ out)                 // [NQ,256] fp32
{
    __shared__ float offx_s[8][16][8];
    __shared__ float offy_s[8][16][8];
    __shared__ float atw_s [8][16][8];
    __shared__ float ref_s [8][8];
    __shared__ unsigned short pA[16][256];   // out-proj A tile (rows 8..15 zero)

    const int tid  = threadIdx.x;
    const int bswz = blockIdx.x & 7;                       // batch -> XCD
    const int iq0  = bswz * 1000 + (blockIdx.x >> 3) * 8;  // 8 queries, same batch

    // zero pA rows 8..15 (one ushort4 per thread, exact)
    {
        const int row = 8 + (tid >> 6);
        const int c4  = (tid & 63) * 4;
        ushort4 z; z.x = 0; z.y = 0; z.z = 0; z.w = 0;
        *(ushort4*)&pA[row][c4] = z;
    }

    if (tid < 64) {
        const int q = tid >> 3, h = tid & 7;
        const float* rowp = offattn + (size_t)(iq0 + q) * 384;
        float lg[16];
        float m = -1e30f;
        #pragma unroll
        for (int i = 0; i < 16; ++i) { lg[i] = rowp[256 + h * 16 + i]; m = fmaxf(m, lg[i]); }
        float s = 0.f;
        #pragma unroll
        for (int i = 0; i < 16; ++i) { lg[i] = __expf(lg[i] - m); s += lg[i]; }
        const float inv = 1.f / s;
        #pragma unroll
        for (int i = 0; i < 16; ++i) atw_s[q][i][h] = lg[i] * inv;
        #pragma unroll
        for (int i = 0; i < 16; ++i) {
            offx_s[q][i][h] = rowp[(h * 16 + i) * 2 + 0];
            offy_s[q][i][h] = rowp[(h * 16 + i) * 2 + 1];
        }
        if (h == 0) {
            #pragma unroll
            for (int i = 0; i < 8; ++i) ref_s[q][i] = refp[(size_t)(iq0 + q) * 8 + i];
        }
    }
    __syncthreads();

    const int q8 = tid >> 6;                 // wave = query
    const int cs = tid & 63;                 // channel slot (h*8 + s4)
    const int h  = cs >> 3;
    const int s4 = cs & 7;                   // 4-channel group within head

    float acc[4] = {0.f, 0.f, 0.f, 0.f};
    const unsigned short* vb = v + (size_t)bswz * LEN_V * 256 + h * 32 + s4 * 4;
    const int Hs[4] = {80, 40, 20, 10};
    const int st[4] = {0, 6400, 8000, 8400};

    #pragma unroll
    for (int lvl = 0; lvl < NLV; ++lvl) {
        const int W = Hs[lvl];
        const float bx = ref_s[q8][lvl * 2 + 0] * (float)W - 0.5f;
        const float by = ref_s[q8][lvl * 2 + 1] * (float)W - 0.5f;
        const unsigned short* vl = vb + (size_t)st[lvl] * 256;
        #pragma unroll
        for (int p = 0; p < NPT; ++p) {
            const int lp = lvl * 4 + p;
            const float x  = bx + offx_s[q8][lp][h];
            const float y  = by + offy_s[q8][lp][h];
            const float at = atw_s[q8][lp][h];
            const float x0f = floorf(x), y0f = floorf(y);
            const float fx = x - x0f, fy = y - y0f;
            const int x0 = (int)x0f, y0 = (int)y0f;
            const int x1 = x0 + 1,   y1 = y0 + 1;
            const int cx0 = min(max(x0, 0), W - 1);
            const int cx1 = min(max(x1, 0), W - 1);
            const int cy0 = min(max(y0, 0), W - 1);
            const int cy1 = min(max(y1, 0), W - 1);
            const float vx0 = (x0 >= 0 && x0 < W) ? 1.f : 0.f;
            const float vx1 = (x1 >= 0 && x1 < W) ? 1.f : 0.f;
            const float vy0 = (y0 >= 0 && y0 < W) ? 1.f : 0.f;
            const float vy1 = (y1 >= 0 && y1 < W) ? 1.f : 0.f;
            const float w00 = at * (1.f - fx) * (1.f - fy) * vx0 * vy0;
            const float w01 = at * fx * (1.f - fy) * vx1 * vy0;
            const float w10 = at * (1.f - fx) * fy * vx0 * vy1;
            const float w11 = at * fx * fy * vx1 * vy1;
            const unsigned short* r0 = vl + (size_t)(cy0 * W) * 256;
            const unsigned short* r1 = vl + (size_t)(cy1 * W) * 256;
            const uint2 d00 = *(const uint2*)(r0 + (size_t)cx0 * 256);
            const uint2 d01 = *(const uint2*)(r0 + (size_t)cx1 * 256);
            const uint2 d10 = *(const uint2*)(r1 + (size_t)cx0 * 256);
            const uint2 d11 = *(const uint2*)(r1 + (size_t)cx1 * 256);
            acc[0] += w00 * asf(d00.x << 16) + w01 * asf(d01.x << 16)
                    + w10 * asf(d10.x << 16) + w11 * asf(d11.x << 16);
            acc[1] += w00 * asf(d00.x & 0xffff0000u) + w01 * asf(d01.x & 0xffff0000u)
                    + w10 * asf(d10.x & 0xffff0000u) + w11 * asf(d11.x & 0xffff0000u);
            acc[2] += w00 * asf(d00.y << 16) + w01 * asf(d01.y << 16)
                    + w10 * asf(d10.y << 16) + w11 * asf(d11.y << 16);
            acc[3] += w00 * asf(d00.y & 0xffff0000u) + w01 * asf(d01.y & 0xffff0000u)
                    + w10 * asf(d10.y & 0xffff0000u) + w11 * asf(d11.y & 0xffff0000u);
        }
    }

    {
        ushort4 o;
        o.x = f2bf(acc[0]); o.y = f2bf(acc[1]);
        o.z = f2bf(acc[2]); o.w = f2bf(acc[3]);
        *(ushort4*)&pA[q8][cs * 4] = o;      // rows 0..7 = the 8 queries
    }
    __syncthreads();

    // ---- out-projection: wave w -> cols w*32..w*32+31 (u0 = w*2, NF=2) ----
    const int l  = tid & 63;
    const int w8 = tid >> 6;                 // 8 waves
    const int lm = l & 15;
    const int lk = l >> 4;

    floatx4 oacc[2];
    #pragma unroll
    for (int j = 0; j < 2; ++j)
        #pragma unroll
        for (int r = 0; r < 4; ++r) oacc[j][r] = 0.f;

    #pragma unroll
    for (int s = 0; s < KS; ++s) {
        const short8 a = *(const short8*)&pA[lm][(s * 4 + lk) * 8];
        #pragma unroll
        for (int j = 0; j < 2; ++j) {
            const short8 b = *(const short8*)(
                wo_f + ((size_t)((w8 * 2 + j) * KS + s) * 64 + l) * 8);
            oacc[j] = __builtin_amdgcn_mfma_f32_16x16x32_bf16(a, b, oacc[j], 0, 0, 0);
        }
    }

    if (lk < 2) {                            // rows 0..7 valid (the 8 queries)
        #pragma unroll
        for (int j = 0; j < 2; ++j) {
            const int col = w8 * 32 + j * 16 + lm;
            const float bo = b_o[col];
            #pragma unroll
            for (int r = 0; r < 4; ++r) {
                const int q = lk * 4 + r;
                out[(size_t)(iq0 + q) * 256 + col] = oacc[j][r] + bo;
            }
        }
    }
}

// ------------------------------- launcher -------------------------------
extern "C" void kernel_launch(void* const* d_in, const int* in_sizes, int n_in,
                              void* d_out, int out_size, void* d_ws, size_t ws_size,
                              hipStream_t stream)
{
    const float* query  = (const float*)d_in[0];
    const float* refp   = (const float*)d_in[1];
    const float* value  = (const float*)d_in[2];
    const float* w_off  = (const float*)d_in[3];
    const float* b_off  = (const float*)d_in[4];
    const float* w_attn = (const float*)d_in[5];
    const float* b_attn = (const float*)d_in[6];
    const float* w_v    = (const float*)d_in[7];
    const float* b_v    = (const float*)d_in[8];
    const float* w_o    = (const float*)d_in[9];
    const float* b_o    = (const float*)d_in[10];
    (void)d_in[11]; (void)d_in[12];  // shapes/starts fixed by problem, hardcoded

    float* out = (float*)d_out;

    // workspace layout (bytes):
    //   v_proj   34,816,000   (68000 x 256 bf16)
    //   offattn  12,288,000   (8000 x 384 f32)
    //   weights     458,752
    char* ws = (char*)d_ws;
    unsigned short* v_proj  = (unsigned short*)ws;
    float*          offattn = (float*)(ws + 34816000);
    unsigned short* wv_f    = (unsigned short*)(ws + 47104000);
    unsigned short* woa_f   = (unsigned short*)(ws + 47235072);
    unsigned short* wo_f    = (unsigned short*)(ws + 47431680);

    dim3 blk(256);

    // 1) weight fragment transform (112 blocks, ~2us)
    hipLaunchKernelGGL(prep_w, dim3(112), blk, 0, stream,
                       w_v, w_off, w_attn, w_o, wv_f, woa_f, wo_f);
    // 2) v-proj + offattn, 3-tile pipelined blocks (836 = 710 + 126)
    hipLaunchKernelGGL(gemm_fused, dim3(836), blk, 0, stream,
                       value, query, wv_f, woa_f, b_v, b_off, b_attn, v_proj, offattn);
    // 3) sampling (4-ch lanes) + softmax + out-projection -> out (fp32)
    hipLaunchKernelGGL(ms_sample_out, dim3(1000), dim3(512), 0, stream,
                       v_proj, offattn, refp, wo_f, b_o, out);
}

// Round 13
// 174.023 us; speedup vs baseline: 1.9612x; 1.9612x over previous
//
#include <hip/hip_runtime.h>
#include <hip/hip_bf16.h>
#include <math.h>

// Problem constants (fixed by setup_inputs)
#define BS     8
#define LQ     1000
#define DMODEL 256
#define NH     8
#define NLV    4
#define NPT    4
#define LEN_V  8500          // 80*80+40*40+20*20+10*10
#define NQ     (BS*LQ)       // 8000
#define MV     (BS*LEN_V)    // 68000
#define KS     8             // K=256 / 32 per mfma step

typedef __attribute__((ext_vector_type(8))) short short8;     // 8 bf16 (4 VGPRs)
typedef __attribute__((ext_vector_type(4))) float floatx4;

static __device__ __forceinline__ unsigned short f2bf(float f) {
    __hip_bfloat16 h = __float2bfloat16(f);   // RNE
    return __builtin_bit_cast(unsigned short, h);
}
static __device__ __forceinline__ float asf(unsigned int u) {
    return __builtin_bit_cast(float, u);
}

// async global->LDS DMA, 16B per lane; LDS dest = wave-uniform base + lane*16.
// Uses NO data registers -- this is what makes the prefetch pipeline fit
// (r12's register-prefetch variant spilled: 84 VGPR + 289MB scratch WRITE).
static __device__ __forceinline__ void dma16(const void* g, void* lds) {
    __builtin_amdgcn_global_load_lds(
        (const __attribute__((address_space(1))) unsigned int*)g,
        (__attribute__((address_space(3))) unsigned int*)lds,
        16, 0, 0);
}

// ---------------------------------------------------------------------------
// PIPELINED v-proj: 8 tiles/block of 32 rows x 256 cols (full width -> A read
// ONCE), fp32 A DMA'd straight to LDS (r3's proven stage/read index math,
// 0 bank conflicts), double-buffered 2x32KB. Counted s_waitcnt vmcnt(8) +
// raw s_barrier + sched_barrier(0): next tile's 8 DMAs stay in flight across
// the barrier (r12 proved this schedule passes determinism; only its register
// staging spilled). fp32->bf16 cvt happens in the K-loop fragment reads.
// ---------------------------------------------------------------------------
static __device__ __forceinline__ void vproj_pipe(
    const float* __restrict__ A, const unsigned short* __restrict__ Bfrag,
    const float* __restrict__ bias, unsigned short* __restrict__ C,
    int t0, int nt, float* __restrict__ Asf /* [2][8192] floats = 64KB */)
{
    const int tid = threadIdx.x;
    const int l   = tid & 63;
    const int w   = tid >> 6;          // wave = 64-col quarter (0..3)
    const int lm  = l & 15;
    const int lk  = l >> 4;

    // B fragments, full width: u0 = w*4 (demotion to L2 reloads is harmless)
    short8 Bf[4][KS];
    #pragma unroll
    for (int j = 0; j < 4; ++j)
        #pragma unroll
        for (int s = 0; s < KS; ++s)
            Bf[j][s] = *(const short8*)(Bfrag + ((size_t)((w * 4 + j) * KS + s) * 64 + l) * 8);

    auto dma_tile = [&](int t, int buf) {
        float* dst = Asf + buf * 8192;
        #pragma unroll
        for (int j = 0; j < 8; ++j) {              // 2048 slots x 16B = 32KB
            const int slot = j * 256 + tid;
            const int row  = slot >> 6;            // 64 x 16B chunks per row
            const int gsrc = (slot & 63) ^ (row & 15);
            dma16(A + (size_t)(t * 32 + row) * 256 + gsrc * 4,
                  dst + (size_t)(j * 256 + w * 64) * 4);   // +lane*16B by HW
        }
    };

    dma_tile(t0, 0);                               // prologue: tile 0 in flight
    int buf = 0;
    for (int i = 0; i < nt; ++i) {
        if (i + 1 < nt) {
            dma_tile(t0 + i + 1, buf ^ 1);         // next tile's 8 DMAs fly
            asm volatile("s_waitcnt vmcnt(8)" ::: "memory");   // current done
        } else {
            asm volatile("s_waitcnt vmcnt(0)" ::: "memory");
        }
        __builtin_amdgcn_s_barrier();
        __builtin_amdgcn_sched_barrier(0);

        const float* As_f = Asf + buf * 8192;
        floatx4 acc[2][4];
        #pragma unroll
        for (int ii = 0; ii < 2; ++ii)
            #pragma unroll
            for (int j = 0; j < 4; ++j)
                #pragma unroll
                for (int r = 0; r < 4; ++r) acc[ii][j][r] = 0.f;

        #pragma unroll
        for (int s = 0; s < KS; ++s) {
            short8 afr[2];
            #pragma unroll
            for (int ii = 0; ii < 2; ++ii) {
                const int row = ii * 16 + lm;      // row & 15 == lm
                const int cb  = s * 8 + lk * 2;
                const float4 a0 = *(const float4*)&As_f[row * 256 + ((cb    ) ^ lm) * 4];
                const float4 a1 = *(const float4*)&As_f[row * 256 + ((cb + 1) ^ lm) * 4];
                afr[ii][0] = (short)f2bf(a0.x); afr[ii][1] = (short)f2bf(a0.y);
                afr[ii][2] = (short)f2bf(a0.z); afr[ii][3] = (short)f2bf(a0.w);
                afr[ii][4] = (short)f2bf(a1.x); afr[ii][5] = (short)f2bf(a1.y);
                afr[ii][6] = (short)f2bf(a1.z); afr[ii][7] = (short)f2bf(a1.w);
            }
            #pragma unroll
            for (int ii = 0; ii < 2; ++ii)
                #pragma unroll
                for (int j = 0; j < 4; ++j)
                    acc[ii][j] = __builtin_amdgcn_mfma_f32_16x16x32_bf16(
                                    afr[ii], Bf[j][s], acc[ii][j], 0, 0, 0);
        }

        // epilogue (M multiple of 32 -- no row guard)
        #pragma unroll
        for (int j = 0; j < 4; ++j) {
            const int col = w * 64 + j * 16 + lm;
            const float bv = bias[col];
            #pragma unroll
            for (int ii = 0; ii < 2; ++ii) {
                const int rbase = (t0 + i) * 32 + ii * 16 + lk * 4;
                #pragma unroll
                for (int r = 0; r < 4; ++r)
                    C[(size_t)(rbase + r) * 256 + col] = f2bf(acc[ii][j][r] + bv);
            }
        }

        __builtin_amdgcn_s_barrier();              // reads done before next
        __builtin_amdgcn_sched_barrier(0);         //   DMA overwrites buf
        buf ^= 1;
    }
}

// ---------------------------------------------------------------------------
// r11 one-tile GEMM (offattn path): 64-row x 128-col, A fp32 reg-staged.
// ---------------------------------------------------------------------------
static __device__ __forceinline__ void gemm_tile(
    const float* __restrict__ Aptr, const unsigned short* __restrict__ Bfrag,
    const float* __restrict__ bias1, const float* __restrict__ bias2, int nsplit,
    void* __restrict__ Cptr, int M, int N, int bn, int bm,
    bool outbf, unsigned short* As /* 16384 shorts = 32KB */)
{
    const int tid = threadIdx.x;
    const int l   = tid & 63;
    const int w   = tid >> 6;
    const int lm  = l & 15;
    const int lk  = l >> 4;
    const int x7  = lm & 7;

    auto aoff = [&](int j) -> size_t {
        const int slot = j * 256 + tid;
        const int row  = slot >> 5;
        const int gc   = (slot & 31) ^ (row & 7);
        int grow = bm * 64 + row; grow = grow < M ? grow : M - 1;
        return (size_t)grow * 256 + gc * 8;
    };

    float4 ra[8][2];
    #pragma unroll
    for (int j = 0; j < 8; ++j) {
        const float* s = Aptr + aoff(j);
        ra[j][0] = *(const float4*)s;
        ra[j][1] = *(const float4*)(s + 4);
    }

    short8 Bf[2][KS];
    const int u0 = bn * 8 + w * 2;
    #pragma unroll
    for (int j = 0; j < 2; ++j)
        #pragma unroll
        for (int s = 0; s < KS; ++s)
            Bf[j][s] = *(const short8*)(Bfrag + ((size_t)((u0 + j) * KS + s) * 64 + l) * 8);

    #pragma unroll
    for (int j = 0; j < 8; ++j) {
        short8 o;
        o[0] = (short)f2bf(ra[j][0].x); o[1] = (short)f2bf(ra[j][0].y);
        o[2] = (short)f2bf(ra[j][0].z); o[3] = (short)f2bf(ra[j][0].w);
        o[4] = (short)f2bf(ra[j][1].x); o[5] = (short)f2bf(ra[j][1].y);
        o[6] = (short)f2bf(ra[j][1].z); o[7] = (short)f2bf(ra[j][1].w);
        *(short8*)&As[(j * 256 + tid) * 8] = o;
    }
    __syncthreads();

    floatx4 acc[4][2];
    #pragma unroll
    for (int i = 0; i < 4; ++i)
        #pragma unroll
        for (int j = 0; j < 2; ++j)
            #pragma unroll
            for (int r = 0; r < 4; ++r) acc[i][j][r] = 0.f;

    #pragma unroll
    for (int s = 0; s < KS; ++s) {
        short8 afr[4];
        #pragma unroll
        for (int i = 0; i < 4; ++i)
            afr[i] = *(const short8*)(
                &As[(i * 16 + lm) * 256 + (((s * 4 + lk) ^ x7)) * 8]);
        #pragma unroll
        for (int i = 0; i < 4; ++i)
            #pragma unroll
            for (int j = 0; j < 2; ++j)
                acc[i][j] = __builtin_amdgcn_mfma_f32_16x16x32_bf16(
                                afr[i], Bf[j][s], acc[i][j], 0, 0, 0);
    }

    #pragma unroll
    for (int j = 0; j < 2; ++j) {
        const int col = bn * 128 + w * 32 + j * 16 + lm;
        const float bv = (bias2 != nullptr && col >= nsplit) ? bias2[col - nsplit]
                                                             : bias1[col];
        #pragma unroll
        for (int i = 0; i < 4; ++i) {
            const int rbase = bm * 64 + i * 16 + lk * 4;
            #pragma unroll
            for (int r = 0; r < 4; ++r) {
                const int row = rbase + r;
                if (row < M) {
                    const float v = acc[i][j][r] + bv;
                    if (outbf)
                        ((unsigned short*)Cptr)[(size_t)row * N + col] = f2bf(v);
                    else
                        ((float*)Cptr)[(size_t)row * N + col] = v;
                }
            }
        }
    }
}

// ---- fused GEMMs (641 blocks):
//      bx <  266 : pipelined v-proj, 8x 32-row full-width tiles (A=value)
//      bx >= 266 : offattn one-tile (125 M-tiles x 3 col-thirds, A=query) ----
__global__ __launch_bounds__(256, 2) void gemm_fused(
    const float* __restrict__ value, const float* __restrict__ query,
    const unsigned short* __restrict__ wv_f, const unsigned short* __restrict__ woa_f,
    const float* __restrict__ b_v, const float* __restrict__ b_off,
    const float* __restrict__ b_attn,
    unsigned short* __restrict__ v_proj, float* __restrict__ offattn)
{
    __shared__ __align__(16) char sh[65536];       // 2x32KB dbuf | 32KB tile
    const int bx = blockIdx.x;
    if (bx < 266) {
        const int t0 = bx * 8;
        const int nt = min(8, 2125 - t0);          // 2125 = 68000/32 tiles
        vproj_pipe(value, wv_f, b_v, v_proj, t0, nt, (float*)sh);
    } else {
        const int ob = bx - 266;
        gemm_tile(query, woa_f, b_off, b_attn, 256,
                  offattn, NQ, 384, ob % 3, ob / 3, false, (unsigned short*)sh);
    }
}

// ---- prep: weight transform to MFMA fragment layout (112 blocks, tiny) ----
__global__ __launch_bounds__(256) void prep_w(
    const float* __restrict__ w_v, const float* __restrict__ w_off,
    const float* __restrict__ w_attn, const float* __restrict__ w_o,
    unsigned short* __restrict__ wv_f, unsigned short* __restrict__ woa_f,
    unsigned short* __restrict__ wo_f)
{
    const int gid = blockIdx.x * 256 + threadIdx.x;     // 28672 total, exact
    int chunk, mode;
    if (gid < 8192)               { chunk = gid;         mode = 0; }
    else if (gid < 8192 + 12288)  { chunk = gid - 8192;  mode = 1; }
    else                          { chunk = gid - 20480; mode = 2; }
    const int l = chunk & 63, s = (chunk >> 6) & 7, u = chunk >> 9;
    short8 o;
    #pragma unroll
    for (int j = 0; j < 8; ++j) {
        const int k = s * 32 + (l >> 4) * 8 + j;
        const int n = u * 16 + (l & 15);
        float v;
        if (mode == 0)      v = w_v[k * 256 + n];
        else if (mode == 1) v = (n < 256) ? w_off[k * 256 + n] : w_attn[k * 128 + (n - 256)];
        else                v = w_o[k * 256 + n];
        o[j] = (short)f2bf(v);
    }
    unsigned short* dp = (mode == 0 ? wv_f : mode == 1 ? woa_f : wo_f)
                         + ((size_t)(u * 8 + s) * 64 + l) * 8;
    *(short8*)dp = o;
}

// ---------------- softmax + sampling + OUT-PROJECTION (512 thr) ----------------
// r11-proven 4-channel sampler, byte-identical. Wave = 1 query, lane = one
// 4-channel slot; 16 points x uint2 gathers; pA -> MFMA out-proj -> fp32 out.
// NO launch-bounds cap (r5/r8: forced caps spill catastrophically).
__global__ __launch_bounds__(512) void ms_sample_out(
    const unsigned short* __restrict__ v,    // [BS,8500,256] bf16
    const float* __restrict__ offattn,       // [NQ,384]: offs[0:256) | logits[256:384)
    const float* __restrict__ refp,          // [NQ,4,2]
    const unsigned short* __restrict__ wo_f, // w_o fragments
    const float* __restrict__ b_o,
    float* __restrict__ out)                 // [NQ,256] fp32
{
    __shared__ float offx_s[8][16][8];
    __shared__ float offy_s[8][16][8];
    __shared__ float atw_s [8][16][8];
    __shared__ float ref_s [8][8];
    __shared__ unsigned short pA[16][256];   // out-proj A tile (rows 8..15 zero)

    const int tid  = threadIdx.x;
    const int bswz = blockIdx.x & 7;                       // batch -> XCD
    const int iq0  = bswz * 1000 + (blockIdx.x >> 3) * 8;  // 8 queries, same batch

    // zero pA rows 8..15 (one ushort4 per thread, exact)
    {
        const int row = 8 + (tid >> 6);
        const int c4  = (tid & 63) * 4;
        ushort4 z; z.x = 0; z.y = 0; z.z = 0; z.w = 0;
        *(ushort4*)&pA[row][c4] = z;
    }

    if (tid < 64) {
        const int q = tid >> 3, h = tid & 7;
        const float* rowp = offattn + (size_t)(iq0 + q) * 384;
        float lg[16];
        float m = -1e30f;
        #pragma unroll
        for (int i = 0; i < 16; ++i) { lg[i] = rowp[256 + h * 16 + i]; m = fmaxf(m, lg[i]); }
        float s = 0.f;
        #pragma unroll
        for (int i = 0; i < 16; ++i) { lg[i] = __expf(lg[i] - m); s += lg[i]; }
        const float inv = 1.f / s;
        #pragma unroll
        for (int i = 0; i < 16; ++i) atw_s[q][i][h] = lg[i] * inv;
        #pragma unroll
        for (int i = 0; i < 16; ++i) {
            offx_s[q][i][h] = rowp[(h * 16 + i) * 2 + 0];
            offy_s[q][i][h] = rowp[(h * 16 + i) * 2 + 1];
        }
        if (h == 0) {
            #pragma unroll
            for (int i = 0; i < 8; ++i) ref_s[q][i] = refp[(size_t)(iq0 + q) * 8 + i];
        }
    }
    __syncthreads();

    const int q8 = tid >> 6;                 // wave = query
    const int cs = tid & 63;                 // channel slot (h*8 + s4)
    const int h  = cs >> 3;
    const int s4 = cs & 7;                   // 4-channel group within head

    float acc[4] = {0.f, 0.f, 0.f, 0.f};
    const unsigned short* vb = v + (size_t)bswz * LEN_V * 256 + h * 32 + s4 * 4;
    const int Hs[4] = {80, 40, 20, 10};
    const int st[4] = {0, 6400, 8000, 8400};

    #pragma unroll
    for (int lvl = 0; lvl < NLV; ++lvl) {
        const int W = Hs[lvl];
        const float bx = ref_s[q8][lvl * 2 + 0] * (float)W - 0.5f;
        const float by = ref_s[q8][lvl * 2 + 1] * (float)W - 0.5f;
        const unsigned short* vl = vb + (size_t)st[lvl] * 256;
        #pragma unroll
        for (int p = 0; p < NPT; ++p) {
            const int lp = lvl * 4 + p;
            const float x  = bx + offx_s[q8][lp][h];
            const float y  = by + offy_s[q8][lp][h];
            const float at = atw_s[q8][lp][h];
            const float x0f = floorf(x), y0f = floorf(y);
            const float fx = x - x0f, fy = y - y0f;
            const int x0 = (int)x0f, y0 = (int)y0f;
            const int x1 = x0 + 1,   y1 = y0 + 1;
            const int cx0 = min(max(x0, 0), W - 1);
            const int cx1 = min(max(x1, 0), W - 1);
            const int cy0 = min(max(y0, 0), W - 1);
            const int cy1 = min(max(y1, 0), W - 1);
            const float vx0 = (x0 >= 0 && x0 < W) ? 1.f : 0.f;
            const float vx1 = (x1 >= 0 && x1 < W) ? 1.f : 0.f;
            const float vy0 = (y0 >= 0 && y0 < W) ? 1.f : 0.f;
            const float vy1 = (y1 >= 0 && y1 < W) ? 1.f : 0.f;
            const float w00 = at * (1.f - fx) * (1.f - fy) * vx0 * vy0;
            const float w01 = at * fx * (1.f - fy) * vx1 * vy0;
            const float w10 = at * (1.f - fx) * fy * vx0 * vy1;
            const float w11 = at * fx * fy * vx1 * vy1;
            const unsigned short* r0 = vl + (size_t)(cy0 * W) * 256;
            const unsigned short* r1 = vl + (size_t)(cy1 * W) * 256;
            const uint2 d00 = *(const uint2*)(r0 + (size_t)cx0 * 256);
            const uint2 d01 = *(const uint2*)(r0 + (size_t)cx1 * 256);
            const uint2 d10 = *(const uint2*)(r1 + (size_t)cx0 * 256);
            const uint2 d11 = *(const uint2*)(r1 + (size_t)cx1 * 256);
            acc[0] += w00 * asf(d00.x << 16) + w01 * asf(d01.x << 16)
                    + w10 * asf(d10.x << 16) + w11 * asf(d11.x << 16);
            acc[1] += w00 * asf(d00.x & 0xffff0000u) + w01 * asf(d01.x & 0xffff0000u)
                    + w10 * asf(d10.x & 0xffff0000u) + w11 * asf(d11.x & 0xffff0000u);
            acc[2] += w00 * asf(d00.y << 16) + w01 * asf(d01.y << 16)
                    + w10 * asf(d10.y << 16) + w11 * asf(d11.y << 16);
            acc[3] += w00 * asf(d00.y & 0xffff0000u) + w01 * asf(d01.y & 0xffff0000u)
                    + w10 * asf(d10.y & 0xffff0000u) + w11 * asf(d11.y & 0xffff0000u);
        }
    }

    {
        ushort4 o;
        o.x = f2bf(acc[0]); o.y = f2bf(acc[1]);
        o.z = f2bf(acc[2]); o.w = f2bf(acc[3]);
        *(ushort4*)&pA[q8][cs * 4] = o;      // rows 0..7 = the 8 queries
    }
    __syncthreads();

    // ---- out-projection: wave w -> cols w*32..w*32+31 (u0 = w*2, NF=2) ----
    const int l  = tid & 63;
    const int w8 = tid >> 6;                 // 8 waves
    const int lm = l & 15;
    const int lk = l >> 4;

    floatx4 oacc[2];
    #pragma unroll
    for (int j = 0; j < 2; ++j)
        #pragma unroll
        for (int r = 0; r < 4; ++r) oacc[j][r] = 0.f;

    #pragma unroll
    for (int s = 0; s < KS; ++s) {
        const short8 a = *(const short8*)&pA[lm][(s * 4 + lk) * 8];
        #pragma unroll
        for (int j = 0; j < 2; ++j) {
            const short8 b = *(const short8*)(
                wo_f + ((size_t)((w8 * 2 + j) * KS + s) * 64 + l) * 8);
            oacc[j] = __builtin_amdgcn_mfma_f32_16x16x32_bf16(a, b, oacc[j], 0, 0, 0);
        }
    }

    if (lk < 2) {                            // rows 0..7 valid (the 8 queries)
        #pragma unroll
        for (int j = 0; j < 2; ++j) {
            const int col = w8 * 32 + j * 16 + lm;
            const float bo = b_o[col];
            #pragma unroll
            for (int r = 0; r < 4; ++r) {
                const int q = lk * 4 + r;
                out[(size_t)(iq0 + q) * 256 + col] = oacc[j][r] + bo;
            }
        }
    }
}

// ------------------------------- launcher -------------------------------
extern "C" void kernel_launch(void* const* d_in, const int* in_sizes, int n_in,
                              void* d_out, int out_size, void* d_ws, size_t ws_size,
                              hipStream_t stream)
{
    const float* query  = (const float*)d_in[0];
    const float* refp   = (const float*)d_in[1];
    const float* value  = (const float*)d_in[2];
    const float* w_off  = (const float*)d_in[3];
    const float* b_off  = (const float*)d_in[4];
    const float* w_attn = (const float*)d_in[5];
    const float* b_attn = (const float*)d_in[6];
    const float* w_v    = (const float*)d_in[7];
    const float* b_v    = (const float*)d_in[8];
    const float* w_o    = (const float*)d_in[9];
    const float* b_o    = (const float*)d_in[10];
    (void)d_in[11]; (void)d_in[12];  // shapes/starts fixed by problem, hardcoded

    float* out = (float*)d_out;

    // workspace layout (bytes):
    //   v_proj   34,816,000   (68000 x 256 bf16)
    //   offattn  12,288,000   (8000 x 384 f32)
    //   weights     458,752
    char* ws = (char*)d_ws;
    unsigned short* v_proj  = (unsigned short*)ws;
    float*          offattn = (float*)(ws + 34816000);
    unsigned short* wv_f    = (unsigned short*)(ws + 47104000);
    unsigned short* woa_f   = (unsigned short*)(ws + 47235072);
    unsigned short* wo_f    = (unsigned short*)(ws + 47431680);

    dim3 blk(256);

    // 1) weight fragment transform (112 blocks, ~2us)
    hipLaunchKernelGGL(prep_w, dim3(112), blk, 0, stream,
                       w_v, w_off, w_attn, w_o, wv_f, woa_f, wo_f);
    // 2) pipelined v-proj + one-tile offattn (641 = 266 + 375)
    hipLaunchKernelGGL(gemm_fused, dim3(641), blk, 0, stream,
                       value, query, wv_f, woa_f, b_v, b_off, b_attn, v_proj, offattn);
    // 3) sampling (4-ch lanes) + softmax + out-projection -> out (fp32)
    hipLaunchKernelGGL(ms_sample_out, dim3(1000), dim3(512), 0, stream,
                       v_proj, offattn, refp, wo_f, b_o, out);
}